// Round 1
// baseline (342.751 us; speedup 1.0000x reference)
//
#include <hip/hip_runtime.h>
#include <hip/hip_bf16.h>
#include <math.h>

// Problem constants (from reference): B=2, S=2048, D_MODEL=1024, H=16, D_K=64
#define SS 2048

typedef __attribute__((ext_vector_type(8))) __bf16 bf16x8;
typedef __attribute__((ext_vector_type(4))) float f32x4;

__device__ __forceinline__ f32x4 mfma16(bf16x8 a, bf16x8 b, f32x4 c) {
  return __builtin_amdgcn_mfma_f32_16x16x32_bf16(a, b, c, 0, 0, 0);
}

__device__ __forceinline__ void gld_lds16(const void* g, void* l) {
  __builtin_amdgcn_global_load_lds(
      (__attribute__((address_space(1))) void*)(g),
      (__attribute__((address_space(3))) void*)(l), 16, 0, 0);
}

// ---------- f32 -> bf16 convert, 8 elems/thread ----------
__global__ void cvt8_kernel(const float* __restrict__ s, __bf16* __restrict__ d, int n) {
  int i = (blockIdx.x * blockDim.x + threadIdx.x) * 8;
  if (i >= n) return;
  float4 a = *reinterpret_cast<const float4*>(s + i);
  float4 b = *reinterpret_cast<const float4*>(s + i + 4);
  bf16x8 o;
  o[0] = (__bf16)a.x; o[1] = (__bf16)a.y; o[2] = (__bf16)a.z; o[3] = (__bf16)a.w;
  o[4] = (__bf16)b.x; o[5] = (__bf16)b.y; o[6] = (__bf16)b.z; o[7] = (__bf16)b.w;
  *reinterpret_cast<bf16x8*>(d + i) = o;
}

// ---------- cos/sin table: tab[s*32+j] = (cos, sin)(pos[s] * 10000^(-2j/64)) ----------
__global__ void trig_kernel(const int* __restrict__ pos, float2* __restrict__ tab) {
  int i = blockIdx.x * blockDim.x + threadIdx.x;
  if (i >= SS * 32) return;
  int s = i >> 5, j = i & 31;
  float p = (float)pos[s];
  float inv = exp2f((float)j * -0.41524101186098283f);  // -(2/64)*log2(10000)
  float f = p * inv;
  float sn, cs;
  sincosf(f, &sn, &cs);
  tab[i] = make_float2(cs, sn);
}

// ---------- C[M][N] = A[M][K] * B[N][K]^T  (both bf16, K-contiguous; m97 structure) ----------
template <typename OutT>
__global__ __launch_bounds__(256) void gemm_bt_kernel(
    const __bf16* __restrict__ A, const __bf16* __restrict__ Bw,
    OutT* __restrict__ C, int M, int N, int K) {
  __shared__ __align__(16) __bf16 lA[128 * 32];
  __shared__ __align__(16) __bf16 lB[128 * 32];
  const int tid = threadIdx.x;
  const int lane = tid & 63;
  const int wave = tid >> 6;
  const int wr = wave >> 1, wc = wave & 1;
  const int m0 = blockIdx.y * 128, n0 = blockIdx.x * 128;

  const f32x4 fzero = {0.f, 0.f, 0.f, 0.f};
  f32x4 acc[4][4];
#pragma unroll
  for (int i = 0; i < 4; ++i)
#pragma unroll
    for (int j = 0; j < 4; ++j) acc[i][j] = fzero;

  const int srow = tid >> 2, scol = (tid & 3) * 8;
  const __bf16* gA = A + (size_t)(m0 + srow) * K + scol;
  const __bf16* gB = Bw + (size_t)(n0 + srow) * K + scol;
  __bf16* sA = lA + tid * 8;
  __bf16* sB = lB + tid * 8;
  const size_t half = (size_t)64 * K;

  const int lrow = lane & 15, lk8 = (lane >> 4) * 8;

  for (int kt = 0; kt < K; kt += 32) {
    gld_lds16(gA + kt, sA);
    gld_lds16(gA + kt + half, sA + 64 * 32);
    gld_lds16(gB + kt, sB);
    gld_lds16(gB + kt + half, sB + 64 * 32);
    __syncthreads();  // drains vmcnt(0): staged tile visible
    bf16x8 af[4], bfr[4];
#pragma unroll
    for (int i = 0; i < 4; ++i)
      af[i] = *reinterpret_cast<const bf16x8*>(lA + (wr * 64 + i * 16 + lrow) * 32 + lk8);
#pragma unroll
    for (int j = 0; j < 4; ++j)
      bfr[j] = *reinterpret_cast<const bf16x8*>(lB + (wc * 64 + j * 16 + lrow) * 32 + lk8);
#pragma unroll
    for (int i = 0; i < 4; ++i)
#pragma unroll
      for (int j = 0; j < 4; ++j) acc[i][j] = mfma16(af[i], bfr[j], acc[i][j]);
    __syncthreads();  // all waves done reading before next stage
  }

  // C/D layout (m89-verified): col = lane&15, row = (lane>>4)*4 + reg
  const int crow = (lane >> 4) * 4, ccol = lane & 15;
#pragma unroll
  for (int i = 0; i < 4; ++i) {
#pragma unroll
    for (int j = 0; j < 4; ++j) {
      int r = m0 + wr * 64 + i * 16 + crow;
      int c = n0 + wc * 64 + j * 16 + ccol;
#pragma unroll
      for (int t = 0; t < 4; ++t) C[(size_t)(r + t) * N + c] = (OutT)acc[i][j][t];
    }
  }
}

// ---------- in-place RoPE on Q and K columns of qkv[4096][3072] ----------
__global__ void rope_kernel(__bf16* qkv, const float2* __restrict__ tab) {
  int i = blockIdx.x * blockDim.x + threadIdx.x;  // exactly 2^22 threads
  int j = i & 31, h = (i >> 5) & 15, s = (i >> 9) & 2047, b = (i >> 20) & 1, p = (i >> 21) & 1;
  float2 cs = tab[(s << 5) | j];
  __bf16* ptr = qkv + (size_t)(b * SS + s) * 3072 + p * 1024 + h * 64 + 2 * j;
  float x1 = (float)ptr[0], x2 = (float)ptr[1];
  ptr[0] = (__bf16)(x1 * cs.x - x2 * cs.y);
  ptr[1] = (__bf16)(x1 * cs.y + x2 * cs.x);
}

// ---------- V transpose: Vt[(b*16+h)*64 + d][s] = V[b,s,h,d] ----------
__global__ __launch_bounds__(256) void vtrans_kernel(const __bf16* __restrict__ qkv,
                                                     __bf16* __restrict__ Vt) {
  __shared__ __bf16 t[64][65];
  const int st = blockIdx.x, h = blockIdx.y, b = blockIdx.z;
  const int tid = threadIdx.x;
  const int sl = tid >> 2, c0 = (tid & 3) * 16;
  const __bf16* src = qkv + (size_t)(b * SS + st * 64 + sl) * 3072 + 2048 + h * 64 + c0;
  bf16x8 a0 = *reinterpret_cast<const bf16x8*>(src);
  bf16x8 a1 = *reinterpret_cast<const bf16x8*>(src + 8);
#pragma unroll
  for (int i = 0; i < 8; ++i) { t[c0 + i][sl] = a0[i]; t[c0 + 8 + i][sl] = a1[i]; }
  __syncthreads();
  __bf16* dst = Vt + (size_t)((b * 16 + h) * 64 + sl) * SS + st * 64 + c0;
  bf16x8 o0, o1;
#pragma unroll
  for (int i = 0; i < 8; ++i) { o0[i] = t[sl][c0 + i]; o1[i] = t[sl][c0 + 8 + i]; }
  *reinterpret_cast<bf16x8*>(dst) = o0;
  *reinterpret_cast<bf16x8*>(dst + 8) = o1;
}

// ---------- causal flash attention: 4 waves/block, 64 q-rows/block, KV tile 64 ----------
__global__ __launch_bounds__(256) void attn_kernel(const __bf16* __restrict__ qkv,
                                                   const __bf16* __restrict__ Vt,
                                                   __bf16* __restrict__ AO) {
  const int qt = blockIdx.x, h = blockIdx.y, b = blockIdx.z;
  const int tid = threadIdx.x;
  const int wave = tid >> 6, lane = tid & 63;
  const int lrow = lane & 15, lk8 = (lane >> 4) * 8, crow = (lane >> 4) * 4;
  const int q0 = qt * 64 + wave * 16;  // wave owns q rows [q0, q0+16)

  __shared__ __align__(16) __bf16 Plds[4][16 * 64];  // per-wave P buffer: no barriers needed
  __bf16* pl = Plds[wave];

  const __bf16* qrow = qkv + (size_t)(b * SS + q0 + lrow) * 3072 + h * 64;
  bf16x8 qa0 = *reinterpret_cast<const bf16x8*>(qrow + lk8);
  bf16x8 qa1 = *reinterpret_cast<const bf16x8*>(qrow + 32 + lk8);

  const __bf16* kbase = qkv + (size_t)(b * SS) * 3072 + 1024 + h * 64;
  const __bf16* vbase = Vt + (size_t)((b * 16 + h) * 64) * SS;

  const f32x4 fzero = {0.f, 0.f, 0.f, 0.f};
  f32x4 oacc[4];
  float mrow[4], lsum[4];
#pragma unroll
  for (int d = 0; d < 4; ++d) oacc[d] = fzero;
#pragma unroll
  for (int r = 0; r < 4; ++r) { mrow[r] = -INFINITY; lsum[r] = 0.f; }

  for (int kt = 0; kt <= qt; ++kt) {
    f32x4 sacc[4];
#pragma unroll
    for (int nt = 0; nt < 4; ++nt) sacc[nt] = fzero;
#pragma unroll
    for (int nt = 0; nt < 4; ++nt) {
      const __bf16* kr = kbase + (size_t)(kt * 64 + nt * 16 + lrow) * 3072;
      bf16x8 kb0 = *reinterpret_cast<const bf16x8*>(kr + lk8);
      bf16x8 kb1 = *reinterpret_cast<const bf16x8*>(kr + 32 + lk8);
      sacc[nt] = mfma16(qa0, kb0, sacc[nt]);
      sacc[nt] = mfma16(qa1, kb1, sacc[nt]);
    }
    float sv[4][4];
    const bool diag = (kt == qt);
#pragma unroll
    for (int nt = 0; nt < 4; ++nt)
#pragma unroll
      for (int r = 0; r < 4; ++r) {
        float x = sacc[nt][r] * 0.125f;  // 1/sqrt(64)
        if (diag && (nt * 16 + lrow > wave * 16 + crow + r)) x = -INFINITY;
        sv[nt][r] = x;
      }
#pragma unroll
    for (int r = 0; r < 4; ++r) {
      float pm = fmaxf(fmaxf(sv[0][r], sv[1][r]), fmaxf(sv[2][r], sv[3][r]));
      pm = fmaxf(pm, __shfl_xor(pm, 1));
      pm = fmaxf(pm, __shfl_xor(pm, 2));
      pm = fmaxf(pm, __shfl_xor(pm, 4));
      pm = fmaxf(pm, __shfl_xor(pm, 8));
      float mn = fmaxf(mrow[r], pm);
      float alpha = __expf(mrow[r] - mn);  // first iter: exp(-inf - finite) = 0
      mrow[r] = mn;
      float rs = 0.f;
#pragma unroll
      for (int nt = 0; nt < 4; ++nt) {
        float pv = __expf(sv[nt][r] - mn);
        rs += pv;
        pl[(crow + r) * 64 + nt * 16 + lrow] = (__bf16)pv;
      }
      rs += __shfl_xor(rs, 1);
      rs += __shfl_xor(rs, 2);
      rs += __shfl_xor(rs, 4);
      rs += __shfl_xor(rs, 8);
      lsum[r] = lsum[r] * alpha + rs;
#pragma unroll
      for (int d = 0; d < 4; ++d) oacc[d][r] *= alpha;
    }
    // PV: A = P[16x64] from LDS, B = Vt rows (d-contiguous in k)
    bf16x8 pa0 = *reinterpret_cast<const bf16x8*>(pl + lrow * 64 + lk8);
    bf16x8 pa1 = *reinterpret_cast<const bf16x8*>(pl + lrow * 64 + 32 + lk8);
#pragma unroll
    for (int d = 0; d < 4; ++d) {
      const __bf16* vr = vbase + (size_t)(d * 16 + lrow) * SS + kt * 64;
      bf16x8 vb0 = *reinterpret_cast<const bf16x8*>(vr + lk8);
      bf16x8 vb1 = *reinterpret_cast<const bf16x8*>(vr + 32 + lk8);
      oacc[d] = mfma16(pa0, vb0, oacc[d]);
      oacc[d] = mfma16(pa1, vb1, oacc[d]);
    }
  }

  __bf16* orow = AO + (size_t)(b * SS + q0 + crow) * 1024 + h * 64;
#pragma unroll
  for (int d = 0; d < 4; ++d) {
#pragma unroll
    for (int r = 0; r < 4; ++r) {
      float ov = oacc[d][r] / lsum[r];
      orow[(size_t)r * 1024 + d * 16 + lrow] = (__bf16)ov;
    }
  }
}

extern "C" void kernel_launch(void* const* d_in, const int* in_sizes, int n_in,
                              void* d_out, int out_size, void* d_ws, size_t ws_size,
                              hipStream_t stream) {
  const float* x  = (const float*)d_in[0];
  const int* pos  = (const int*)d_in[1];
  const float* Wq = (const float*)d_in[2];
  const float* Wk = (const float*)d_in[3];
  const float* Wv = (const float*)d_in[4];
  const float* Wo = (const float*)d_in[5];

  // workspace layout (all bf16 except trig table): ~56.5 MB total
  __bf16* xb  = (__bf16*)d_ws;                        // [4096][1024]
  __bf16* Wb  = xb + (size_t)4096 * 1024;             // [4096][1024] = Wq;Wk;Wv;Wo stacked
  __bf16* qkv = Wb + (size_t)4096 * 1024;             // [4096][3072] (q|k|v cols)
  __bf16* Vt  = qkv + (size_t)4096 * 3072;            // [2*16*64][2048]
  __bf16* ao  = Vt + (size_t)2048 * 2048;             // [4096][1024]
  float2* tab = (float2*)(ao + (size_t)4096 * 1024);  // [2048*32]

  cvt8_kernel<<<2048, 256, 0, stream>>>(x, xb, 4096 * 1024);
  cvt8_kernel<<<512, 256, 0, stream>>>(Wq, Wb, 1024 * 1024);
  cvt8_kernel<<<512, 256, 0, stream>>>(Wk, Wb + (size_t)1024 * 1024, 1024 * 1024);
  cvt8_kernel<<<512, 256, 0, stream>>>(Wv, Wb + (size_t)2 * 1024 * 1024, 1024 * 1024);
  cvt8_kernel<<<512, 256, 0, stream>>>(Wo, Wb + (size_t)3 * 1024 * 1024, 1024 * 1024);
  trig_kernel<<<256, 256, 0, stream>>>(pos, tab);

  // fused QKV projection: [4096][1024] x [3072][1024]^T -> [4096][3072]
  gemm_bt_kernel<__bf16><<<dim3(24, 32), 256, 0, stream>>>(xb, Wb, qkv, 4096, 3072, 1024);
  rope_kernel<<<16384, 256, 0, stream>>>(qkv, tab);
  vtrans_kernel<<<dim3(32, 16, 2), 256, 0, stream>>>(qkv, Vt);
  attn_kernel<<<dim3(32, 16, 2), 256, 0, stream>>>(qkv, Vt, ao);
  // output projection: [4096][1024] x [1024][1024]^T -> f32 out
  gemm_bt_kernel<float><<<dim3(8, 32), 256, 0, stream>>>(ao, Wb + (size_t)3 * 1024 * 1024,
                                                         (float*)d_out, 4096, 1024, 1024);
}

// Round 2
// 214.457 us; speedup vs baseline: 1.5982x; 1.5982x over previous
//
#include <hip/hip_runtime.h>
#include <hip/hip_bf16.h>
#include <math.h>

// Problem constants (from reference): B=2, S=2048, D_MODEL=1024, H=16, D_K=64
#define SS 2048

typedef __attribute__((ext_vector_type(8))) __bf16 bf16x8;
typedef __attribute__((ext_vector_type(4))) float f32x4;

__device__ __forceinline__ f32x4 mfma16(bf16x8 a, bf16x8 b, f32x4 c) {
  return __builtin_amdgcn_mfma_f32_16x16x32_bf16(a, b, c, 0, 0, 0);
}

__device__ __forceinline__ void gld_lds16(const void* g, void* l) {
  __builtin_amdgcn_global_load_lds(
      (__attribute__((address_space(1))) void*)(g),
      (__attribute__((address_space(3))) void*)(l), 16, 0, 0);
}

// ---------- f32 -> bf16 convert, 8 elems/thread ----------
__global__ void cvt8_kernel(const float* __restrict__ s, __bf16* __restrict__ d, int n) {
  int i = (blockIdx.x * blockDim.x + threadIdx.x) * 8;
  if (i >= n) return;
  float4 a = *reinterpret_cast<const float4*>(s + i);
  float4 b = *reinterpret_cast<const float4*>(s + i + 4);
  bf16x8 o;
  o[0] = (__bf16)a.x; o[1] = (__bf16)a.y; o[2] = (__bf16)a.z; o[3] = (__bf16)a.w;
  o[4] = (__bf16)b.x; o[5] = (__bf16)b.y; o[6] = (__bf16)b.z; o[7] = (__bf16)b.w;
  *reinterpret_cast<bf16x8*>(d + i) = o;
}

// ---------- cos/sin table: tab[s*32+j] = (cos, sin)(pos[s] * 10000^(-2j/64)) ----------
__global__ void trig_kernel(const int* __restrict__ pos, float2* __restrict__ tab) {
  int i = blockIdx.x * blockDim.x + threadIdx.x;
  if (i >= SS * 32) return;
  int s = i >> 5, j = i & 31;
  float p = (float)pos[s];
  float inv = exp2f((float)j * -0.41524101186098283f);  // -(2/64)*log2(10000)
  float f = p * inv;
  float sn, cs;
  sincosf(f, &sn, &cs);
  tab[i] = make_float2(cs, sn);
}

// ---------- C[M][N] = A[M][K] * B[N][K]^T  (both bf16, K-contiguous; m97 structure) ----------
template <typename OutT>
__global__ __launch_bounds__(256) void gemm_bt_kernel(
    const __bf16* __restrict__ A, const __bf16* __restrict__ Bw,
    OutT* __restrict__ C, int M, int N, int K) {
  __shared__ __align__(16) __bf16 lA[128 * 32];
  __shared__ __align__(16) __bf16 lB[128 * 32];
  const int tid = threadIdx.x;
  const int lane = tid & 63;
  const int wave = tid >> 6;
  const int wr = wave >> 1, wc = wave & 1;
  const int m0 = blockIdx.y * 128, n0 = blockIdx.x * 128;

  const f32x4 fzero = {0.f, 0.f, 0.f, 0.f};
  f32x4 acc[4][4];
#pragma unroll
  for (int i = 0; i < 4; ++i)
#pragma unroll
    for (int j = 0; j < 4; ++j) acc[i][j] = fzero;

  const int srow = tid >> 2, scol = (tid & 3) * 8;
  const __bf16* gA = A + (size_t)(m0 + srow) * K + scol;
  const __bf16* gB = Bw + (size_t)(n0 + srow) * K + scol;
  __bf16* sA = lA + tid * 8;
  __bf16* sB = lB + tid * 8;
  const size_t half = (size_t)64 * K;

  const int lrow = lane & 15, lk8 = (lane >> 4) * 8;

  for (int kt = 0; kt < K; kt += 32) {
    gld_lds16(gA + kt, sA);
    gld_lds16(gA + kt + half, sA + 64 * 32);
    gld_lds16(gB + kt, sB);
    gld_lds16(gB + kt + half, sB + 64 * 32);
    __syncthreads();  // drains vmcnt(0): staged tile visible
    bf16x8 af[4], bfr[4];
#pragma unroll
    for (int i = 0; i < 4; ++i)
      af[i] = *reinterpret_cast<const bf16x8*>(lA + (wr * 64 + i * 16 + lrow) * 32 + lk8);
#pragma unroll
    for (int j = 0; j < 4; ++j)
      bfr[j] = *reinterpret_cast<const bf16x8*>(lB + (wc * 64 + j * 16 + lrow) * 32 + lk8);
#pragma unroll
    for (int i = 0; i < 4; ++i)
#pragma unroll
      for (int j = 0; j < 4; ++j) acc[i][j] = mfma16(af[i], bfr[j], acc[i][j]);
    __syncthreads();  // all waves done reading before next stage
  }

  // C/D layout (m89-verified): col = lane&15, row = (lane>>4)*4 + reg
  const int crow = (lane >> 4) * 4, ccol = lane & 15;
#pragma unroll
  for (int i = 0; i < 4; ++i) {
#pragma unroll
    for (int j = 0; j < 4; ++j) {
      int r = m0 + wr * 64 + i * 16 + crow;
      int c = n0 + wc * 64 + j * 16 + ccol;
#pragma unroll
      for (int t = 0; t < 4; ++t) C[(size_t)(r + t) * N + c] = (OutT)acc[i][j][t];
    }
  }
}

// ---------- in-place RoPE on Q and K columns of qkv[4096][3072] ----------
__global__ void rope_kernel(__bf16* qkv, const float2* __restrict__ tab) {
  int i = blockIdx.x * blockDim.x + threadIdx.x;  // exactly 2^22 threads
  int j = i & 31, h = (i >> 5) & 15, s = (i >> 9) & 2047, b = (i >> 20) & 1, p = (i >> 21) & 1;
  float2 cs = tab[(s << 5) | j];
  __bf16* ptr = qkv + (size_t)(b * SS + s) * 3072 + p * 1024 + h * 64 + 2 * j;
  float x1 = (float)ptr[0], x2 = (float)ptr[1];
  ptr[0] = (__bf16)(x1 * cs.x - x2 * cs.y);
  ptr[1] = (__bf16)(x1 * cs.y + x2 * cs.x);
}

// ---------- V transpose: Vt[(b*16+h)*64 + d][s] = V[b,s,h,d] ----------
__global__ __launch_bounds__(256) void vtrans_kernel(const __bf16* __restrict__ qkv,
                                                     __bf16* __restrict__ Vt) {
  __shared__ __bf16 t[64][65];
  const int st = blockIdx.x, h = blockIdx.y, b = blockIdx.z;
  const int tid = threadIdx.x;
  const int sl = tid >> 2, c0 = (tid & 3) * 16;
  const __bf16* src = qkv + (size_t)(b * SS + st * 64 + sl) * 3072 + 2048 + h * 64 + c0;
  bf16x8 a0 = *reinterpret_cast<const bf16x8*>(src);
  bf16x8 a1 = *reinterpret_cast<const bf16x8*>(src + 8);
#pragma unroll
  for (int i = 0; i < 8; ++i) { t[c0 + i][sl] = a0[i]; t[c0 + 8 + i][sl] = a1[i]; }
  __syncthreads();
  __bf16* dst = Vt + (size_t)((b * 16 + h) * 64 + sl) * SS + st * 64 + c0;
  bf16x8 o0, o1;
#pragma unroll
  for (int i = 0; i < 8; ++i) { o0[i] = t[sl][c0 + i]; o1[i] = t[sl][c0 + 8 + i]; }
  *reinterpret_cast<bf16x8*>(dst) = o0;
  *reinterpret_cast<bf16x8*>(dst + 8) = o1;
}

// ---------- causal flash attention ----------
// 4 waves/block, 128 q-rows/block (32/wave), KV tile 64, double-buffered
// K/V LDS staging via global_load_lds with source-side XOR swizzle (m173).
__global__ __launch_bounds__(256, 2) void attn_kernel(const __bf16* __restrict__ qkv,
                                                      const __bf16* __restrict__ Vt,
                                                      __bf16* __restrict__ AO) {
  const int qt = (int)gridDim.x - 1 - (int)blockIdx.x;  // longest-first
  const int h = blockIdx.y, b = blockIdx.z;
  const int tid = threadIdx.x;
  const int wave = tid >> 6, lane = tid & 63;
  const int lrow = lane & 15, khi = lane >> 4, crow = khi * 4;
  const int q0 = qt * 128 + wave * 32;  // wave owns q rows [q0, q0+32)
  const int qlast = q0 + 31;

  __shared__ __align__(16) __bf16 lK[2][64 * 64];
  __shared__ __align__(16) __bf16 lV[2][64 * 64];
  __shared__ __align__(16) __bf16 lP[4][32 * 72];
  __bf16* pl = lP[wave];

  // Q fragments: rows q0 + rg*16 + lrow, k-halves kk
  bf16x8 qa[2][2];
#pragma unroll
  for (int rg = 0; rg < 2; ++rg) {
    const __bf16* qr = qkv + (size_t)(b * SS + q0 + rg * 16 + lrow) * 3072 + h * 64;
#pragma unroll
    for (int kk = 0; kk < 2; ++kk)
      qa[rg][kk] = *reinterpret_cast<const bf16x8*>(qr + kk * 32 + khi * 8);
  }

  const __bf16* kbase = qkv + (size_t)(b * SS) * 3072 + 1024 + h * 64;
  const __bf16* vbase = Vt + (size_t)((b * 16 + h) * 64) * SS;

  // staging: row = tid>>3 (and +32), 16B chunk cg=tid&7, source col XOR-swizzled
  const int srow = tid >> 3, scg = tid & 7;
  const int ssc = 8 * (scg ^ (srow & 7));
  const __bf16* kG0 = kbase + (size_t)srow * 3072 + ssc;
  const __bf16* vG0 = vbase + (size_t)srow * SS + ssc;

  const f32x4 fzero = {0.f, 0.f, 0.f, 0.f};
  f32x4 oacc[2][4];
  float mrow[2][4], lsum[2][4];
#pragma unroll
  for (int rg = 0; rg < 2; ++rg) {
#pragma unroll
    for (int d = 0; d < 4; ++d) oacc[rg][d] = fzero;
#pragma unroll
    for (int r = 0; r < 4; ++r) { mrow[rg][r] = -INFINITY; lsum[rg][r] = 0.f; }
  }

  const int nkt = 2 * qt + 2;

  // prologue: stage tile 0 into buf 0
  {
    gld_lds16(kG0, lK[0] + tid * 8);
    gld_lds16(kG0 + (size_t)32 * 3072, lK[0] + tid * 8 + 2048);
    gld_lds16(vG0, lV[0] + tid * 8);
    gld_lds16(vG0 + (size_t)32 * SS, lV[0] + tid * 8 + 2048);
  }
  __syncthreads();

  for (int kt = 0; kt < nkt; ++kt) {
    const int buf = kt & 1;
    if (kt + 1 < nkt) {  // prefetch next tile into other buffer
      const __bf16* kG = kG0 + (size_t)(kt + 1) * 64 * 3072;
      const __bf16* vG = vG0 + (kt + 1) * 64;
      gld_lds16(kG, lK[buf ^ 1] + tid * 8);
      gld_lds16(kG + (size_t)32 * 3072, lK[buf ^ 1] + tid * 8 + 2048);
      gld_lds16(vG, lV[buf ^ 1] + tid * 8);
      gld_lds16(vG + (size_t)32 * SS, lV[buf ^ 1] + tid * 8 + 2048);
    }

    if (kt * 64 <= qlast) {  // wave-active (wave-uniform branch)
      const int kvb = kt * 64;
      // ---- QK^T: sacc[rg][nt] over 16x16 tiles, K=64 in 2 halves ----
      f32x4 sacc[2][4];
#pragma unroll
      for (int rg = 0; rg < 2; ++rg)
#pragma unroll
        for (int nt = 0; nt < 4; ++nt) sacc[rg][nt] = fzero;
#pragma unroll
      for (int nt = 0; nt < 4; ++nt) {
        const int row = nt * 16 + lrow, r7 = lrow & 7;
#pragma unroll
        for (int kk = 0; kk < 2; ++kk) {
          bf16x8 kb = *reinterpret_cast<const bf16x8*>(
              lK[buf] + row * 64 + 8 * (((kk << 2) | khi) ^ r7));
          sacc[0][nt] = mfma16(qa[0][kk], kb, sacc[0][nt]);
          sacc[1][nt] = mfma16(qa[1][kk], kb, sacc[1][nt]);
        }
      }
      // ---- scale + causal mask ----
      const bool needmask = (kvb + 63 > q0);
#pragma unroll
      for (int rg = 0; rg < 2; ++rg)
#pragma unroll
        for (int nt = 0; nt < 4; ++nt)
#pragma unroll
          for (int r = 0; r < 4; ++r) {
            float x = sacc[rg][nt][r] * 0.125f;
            if (needmask && (kvb + nt * 16 + lrow > q0 + rg * 16 + crow + r))
              x = -INFINITY;
            sacc[rg][nt][r] = x;
          }
      // ---- online softmax (16-lane butterfly over lrow) ----
#pragma unroll
      for (int rg = 0; rg < 2; ++rg) {
#pragma unroll
        for (int r = 0; r < 4; ++r) {
          float pm = fmaxf(fmaxf(sacc[rg][0][r], sacc[rg][1][r]),
                           fmaxf(sacc[rg][2][r], sacc[rg][3][r]));
          pm = fmaxf(pm, __shfl_xor(pm, 1));
          pm = fmaxf(pm, __shfl_xor(pm, 2));
          pm = fmaxf(pm, __shfl_xor(pm, 4));
          pm = fmaxf(pm, __shfl_xor(pm, 8));
          float mn = fmaxf(mrow[rg][r], pm);
          float alpha = __expf(mrow[rg][r] - mn);
          mrow[rg][r] = mn;
          float rs = 0.f;
#pragma unroll
          for (int nt = 0; nt < 4; ++nt) {
            float pv = __expf(sacc[rg][nt][r] - mn);
            rs += pv;
            pl[(rg * 16 + crow + r) * 72 + nt * 16 + lrow] = (__bf16)pv;
          }
          rs += __shfl_xor(rs, 1);
          rs += __shfl_xor(rs, 2);
          rs += __shfl_xor(rs, 4);
          rs += __shfl_xor(rs, 8);
          lsum[rg][r] = lsum[rg][r] * alpha + rs;
#pragma unroll
          for (int d = 0; d < 4; ++d) oacc[rg][d][r] *= alpha;
        }
      }
      // ---- PV: A = P (LDS, padded 72), B = V-tile (LDS, swizzled) ----
      bf16x8 pa[2][2];
#pragma unroll
      for (int rg = 0; rg < 2; ++rg)
#pragma unroll
        for (int kk = 0; kk < 2; ++kk)
          pa[rg][kk] = *reinterpret_cast<const bf16x8*>(
              pl + (rg * 16 + lrow) * 72 + kk * 32 + khi * 8);
#pragma unroll
      for (int d = 0; d < 4; ++d) {
        const int row = d * 16 + lrow, r7 = lrow & 7;
#pragma unroll
        for (int kk = 0; kk < 2; ++kk) {
          bf16x8 vb = *reinterpret_cast<const bf16x8*>(
              lV[buf] + row * 64 + 8 * (((kk << 2) | khi) ^ r7));
          oacc[0][d] = mfma16(pa[0][kk], vb, oacc[0][d]);
          oacc[1][d] = mfma16(pa[1][kk], vb, oacc[1][d]);
        }
      }
    }
    __syncthreads();  // staged loads drained (vmcnt 0) + all waves done with buf
  }

  // epilogue
#pragma unroll
  for (int rg = 0; rg < 2; ++rg) {
    __bf16* orow = AO + (size_t)(b * SS + q0 + rg * 16 + crow) * 1024 + h * 64;
#pragma unroll
    for (int d = 0; d < 4; ++d)
#pragma unroll
      for (int r = 0; r < 4; ++r)
        orow[(size_t)r * 1024 + d * 16 + lrow] = (__bf16)(oacc[rg][d][r] / lsum[rg][r]);
  }
}

extern "C" void kernel_launch(void* const* d_in, const int* in_sizes, int n_in,
                              void* d_out, int out_size, void* d_ws, size_t ws_size,
                              hipStream_t stream) {
  const float* x  = (const float*)d_in[0];
  const int* pos  = (const int*)d_in[1];
  const float* Wq = (const float*)d_in[2];
  const float* Wk = (const float*)d_in[3];
  const float* Wv = (const float*)d_in[4];
  const float* Wo = (const float*)d_in[5];

  // workspace layout (all bf16 except trig table): ~56.5 MB total
  __bf16* xb  = (__bf16*)d_ws;                        // [4096][1024]
  __bf16* Wb  = xb + (size_t)4096 * 1024;             // [4096][1024] = Wq;Wk;Wv;Wo stacked
  __bf16* qkv = Wb + (size_t)4096 * 1024;             // [4096][3072] (q|k|v cols)
  __bf16* Vt  = qkv + (size_t)4096 * 3072;            // [2*16*64][2048]
  __bf16* ao  = Vt + (size_t)2048 * 2048;             // [4096][1024]
  float2* tab = (float2*)(ao + (size_t)4096 * 1024);  // [2048*32]

  cvt8_kernel<<<2048, 256, 0, stream>>>(x, xb, 4096 * 1024);
  cvt8_kernel<<<512, 256, 0, stream>>>(Wq, Wb, 1024 * 1024);
  cvt8_kernel<<<512, 256, 0, stream>>>(Wk, Wb + (size_t)1024 * 1024, 1024 * 1024);
  cvt8_kernel<<<512, 256, 0, stream>>>(Wv, Wb + (size_t)2 * 1024 * 1024, 1024 * 1024);
  cvt8_kernel<<<512, 256, 0, stream>>>(Wo, Wb + (size_t)3 * 1024 * 1024, 1024 * 1024);
  trig_kernel<<<256, 256, 0, stream>>>(pos, tab);

  // fused QKV projection: [4096][1024] x [3072][1024]^T -> [4096][3072]
  gemm_bt_kernel<__bf16><<<dim3(24, 32), 256, 0, stream>>>(xb, Wb, qkv, 4096, 3072, 1024);
  rope_kernel<<<16384, 256, 0, stream>>>(qkv, tab);
  vtrans_kernel<<<dim3(32, 16, 2), 256, 0, stream>>>(qkv, Vt);
  attn_kernel<<<dim3(16, 16, 2), 256, 0, stream>>>(qkv, Vt, ao);
  // output projection: [4096][1024] x [1024][1024]^T -> f32 out
  gemm_bt_kernel<float><<<dim3(8, 32), 256, 0, stream>>>(ao, Wb + (size_t)3 * 1024 * 1024,
                                                         (float*)d_out, 4096, 1024, 1024);
}

// Round 3
// 152.961 us; speedup vs baseline: 2.2408x; 1.4020x over previous
//
#include <hip/hip_runtime.h>
#include <hip/hip_bf16.h>
#include <math.h>

// Problem constants (from reference): B=2, S=2048, D_MODEL=1024, H=16, D_K=64
#define SS 2048

typedef __attribute__((ext_vector_type(8))) __bf16 bf16x8;
typedef __attribute__((ext_vector_type(4))) float f32x4;
typedef __attribute__((ext_vector_type(16))) float f32x16;
typedef __attribute__((ext_vector_type(4))) unsigned int u32x4;

__device__ __forceinline__ f32x4 mfma16(bf16x8 a, bf16x8 b, f32x4 c) {
  return __builtin_amdgcn_mfma_f32_16x16x32_bf16(a, b, c, 0, 0, 0);
}
__device__ __forceinline__ f32x16 mfma32(bf16x8 a, bf16x8 b, f32x16 c) {
  return __builtin_amdgcn_mfma_f32_32x32x16_bf16(a, b, c, 0, 0, 0);
}

__device__ __forceinline__ void gld_lds16(const void* g, void* l) {
  __builtin_amdgcn_global_load_lds(
      (__attribute__((address_space(1))) void*)(g),
      (__attribute__((address_space(3))) void*)(l), 16, 0, 0);
}

#if __has_builtin(__builtin_amdgcn_exp2f)
#define EXP2F(x) __builtin_amdgcn_exp2f(x)
#else
#define EXP2F(x) __expf(0.69314718056f * (x))
#endif

__device__ __forceinline__ unsigned int cvtpk_bf16(float lo, float hi) {
  unsigned int r;
  asm("v_cvt_pk_bf16_f32 %0, %1, %2" : "=v"(r) : "v"(lo), "v"(hi));
  return r;
}
__device__ __forceinline__ void swap32(unsigned int& x, unsigned int& y) {
  asm("v_permlane32_swap_b32 %0, %1" : "+v"(x), "+v"(y));
}

// ---------- f32 -> bf16 convert, 8 elems/thread ----------
__global__ void cvt8_kernel(const float* __restrict__ s, __bf16* __restrict__ d, int n) {
  int i = (blockIdx.x * blockDim.x + threadIdx.x) * 8;
  if (i >= n) return;
  float4 a = *reinterpret_cast<const float4*>(s + i);
  float4 b = *reinterpret_cast<const float4*>(s + i + 4);
  bf16x8 o;
  o[0] = (__bf16)a.x; o[1] = (__bf16)a.y; o[2] = (__bf16)a.z; o[3] = (__bf16)a.w;
  o[4] = (__bf16)b.x; o[5] = (__bf16)b.y; o[6] = (__bf16)b.z; o[7] = (__bf16)b.w;
  *reinterpret_cast<bf16x8*>(d + i) = o;
}

// ---------- cos/sin table ----------
__global__ void trig_kernel(const int* __restrict__ pos, float2* __restrict__ tab) {
  int i = blockIdx.x * blockDim.x + threadIdx.x;
  if (i >= SS * 32) return;
  int s = i >> 5, j = i & 31;
  float p = (float)pos[s];
  float inv = exp2f((float)j * -0.41524101186098283f);  // -(2/64)*log2(10000)
  float f = p * inv;
  float sn, cs;
  sincosf(f, &sn, &cs);
  tab[i] = make_float2(cs, sn);
}

// ---------- C[M][N] = A[M][K] * B[N][K]^T  (m97 structure) ----------
template <typename OutT>
__global__ __launch_bounds__(256) void gemm_bt_kernel(
    const __bf16* __restrict__ A, const __bf16* __restrict__ Bw,
    OutT* __restrict__ C, int M, int N, int K) {
  __shared__ __align__(16) __bf16 lA[128 * 32];
  __shared__ __align__(16) __bf16 lB[128 * 32];
  const int tid = threadIdx.x;
  const int lane = tid & 63;
  const int wave = tid >> 6;
  const int wr = wave >> 1, wc = wave & 1;
  const int m0 = blockIdx.y * 128, n0 = blockIdx.x * 128;

  const f32x4 fzero = {0.f, 0.f, 0.f, 0.f};
  f32x4 acc[4][4];
#pragma unroll
  for (int i = 0; i < 4; ++i)
#pragma unroll
    for (int j = 0; j < 4; ++j) acc[i][j] = fzero;

  const int srow = tid >> 2, scol = (tid & 3) * 8;
  const __bf16* gA = A + (size_t)(m0 + srow) * K + scol;
  const __bf16* gB = Bw + (size_t)(n0 + srow) * K + scol;
  __bf16* sA = lA + tid * 8;
  __bf16* sB = lB + tid * 8;
  const size_t half = (size_t)64 * K;

  const int lrow = lane & 15, lk8 = (lane >> 4) * 8;

  for (int kt = 0; kt < K; kt += 32) {
    gld_lds16(gA + kt, sA);
    gld_lds16(gA + kt + half, sA + 64 * 32);
    gld_lds16(gB + kt, sB);
    gld_lds16(gB + kt + half, sB + 64 * 32);
    __syncthreads();
    bf16x8 af[4], bfr[4];
#pragma unroll
    for (int i = 0; i < 4; ++i)
      af[i] = *reinterpret_cast<const bf16x8*>(lA + (wr * 64 + i * 16 + lrow) * 32 + lk8);
#pragma unroll
    for (int j = 0; j < 4; ++j)
      bfr[j] = *reinterpret_cast<const bf16x8*>(lB + (wc * 64 + j * 16 + lrow) * 32 + lk8);
#pragma unroll
    for (int i = 0; i < 4; ++i)
#pragma unroll
      for (int j = 0; j < 4; ++j) acc[i][j] = mfma16(af[i], bfr[j], acc[i][j]);
    __syncthreads();
  }

  const int crow = (lane >> 4) * 4, ccol = lane & 15;
#pragma unroll
  for (int i = 0; i < 4; ++i) {
#pragma unroll
    for (int j = 0; j < 4; ++j) {
      int r = m0 + wr * 64 + i * 16 + crow;
      int c = n0 + wc * 64 + j * 16 + ccol;
#pragma unroll
      for (int t = 0; t < 4; ++t) C[(size_t)(r + t) * N + c] = (OutT)acc[i][j][t];
    }
  }
}

// ---------- in-place RoPE on Q and K columns of qkv[4096][3072] ----------
__global__ void rope_kernel(__bf16* qkv, const float2* __restrict__ tab) {
  int i = blockIdx.x * blockDim.x + threadIdx.x;  // exactly 2^22 threads
  int j = i & 31, h = (i >> 5) & 15, s = (i >> 9) & 2047, b = (i >> 20) & 1, p = (i >> 21) & 1;
  float2 cs = tab[(s << 5) | j];
  __bf16* ptr = qkv + (size_t)(b * SS + s) * 3072 + p * 1024 + h * 64 + 2 * j;
  float x1 = (float)ptr[0], x2 = (float)ptr[1];
  ptr[0] = (__bf16)(x1 * cs.x - x2 * cs.y);
  ptr[1] = (__bf16)(x1 * cs.y + x2 * cs.x);
}

// ---------- V transpose: Vt[(b*16+h)*64 + d][s] = V[b,s,h,d] ----------
__global__ __launch_bounds__(256) void vtrans_kernel(const __bf16* __restrict__ qkv,
                                                     __bf16* __restrict__ Vt) {
  __shared__ __bf16 t[64][65];
  const int st = blockIdx.x, h = blockIdx.y, b = blockIdx.z;
  const int tid = threadIdx.x;
  const int sl = tid >> 2, c0 = (tid & 3) * 16;
  const __bf16* src = qkv + (size_t)(b * SS + st * 64 + sl) * 3072 + 2048 + h * 64 + c0;
  bf16x8 a0 = *reinterpret_cast<const bf16x8*>(src);
  bf16x8 a1 = *reinterpret_cast<const bf16x8*>(src + 8);
#pragma unroll
  for (int i = 0; i < 8; ++i) { t[c0 + i][sl] = a0[i]; t[c0 + 8 + i][sl] = a1[i]; }
  __syncthreads();
  __bf16* dst = Vt + (size_t)((b * 16 + h) * 64 + sl) * SS + st * 64 + c0;
  bf16x8 o0, o1;
#pragma unroll
  for (int i = 0; i < 8; ++i) { o0[i] = t[sl][c0 + i]; o1[i] = t[sl][c0 + 8 + i]; }
  *reinterpret_cast<bf16x8*>(dst) = o0;
  *reinterpret_cast<bf16x8*>(dst + 8) = o1;
}

// ---------- causal flash attention, 32x32 swapped-operand structure ----------
// 4 waves/block, 32 q-rows/wave (128/block), KV tile 64, dbuf LDS K/V via
// global_load_lds with source-side XOR swizzle. In-register softmax:
// lane owns q-row (lane&31); row-reduce = in-lane + one shfl_xor(32).
// P -> bf16 via cvt_pk + permlane32_swap directly into PV B-fragments.
// PV computes O^T = V^T * P^T so rescale stays lane-local.
#define CEXP 0.18033688011112042f  // log2(e)/8

__global__ __launch_bounds__(256, 2) void attn_kernel(const __bf16* __restrict__ qkv,
                                                      const __bf16* __restrict__ Vt,
                                                      __bf16* __restrict__ AO) {
  const int qt = (int)gridDim.x - 1 - (int)blockIdx.x;  // longest-first
  const int h = blockIdx.y, b = blockIdx.z;
  const int tid = threadIdx.x;
  const int wave = tid >> 6, lane = tid & 63;
  const int q32 = lane & 31, hi = lane >> 5;
  const int qw0 = qt * 128 + wave * 32;
  const int q = qw0 + q32;

  __shared__ __align__(16) __bf16 lK[2][64 * 64];
  __shared__ __align__(16) __bf16 lV[2][64 * 64];
  __shared__ __align__(16) __bf16 lO[4][32 * 72];

  // Q fragments (B-operand of QK^T): lane holds Q[q][slot*16 + hi*8 + 0..7]
  bf16x8 qb[4];
  {
    const __bf16* qr = qkv + (size_t)(b * SS + q) * 3072 + h * 64;
#pragma unroll
    for (int slot = 0; slot < 4; ++slot)
      qb[slot] = *reinterpret_cast<const bf16x8*>(qr + slot * 16 + hi * 8);
  }

  const __bf16* kbase = qkv + (size_t)(b * SS) * 3072 + 1024 + h * 64;
  const __bf16* vbase = Vt + (size_t)((b * 16 + h) * 64) * SS;

  // staging: LDS row r = tid>>3, chunk c = tid&7; source chunk pre-XOR'd
  const int srow = tid >> 3, scg = tid & 7;
  const int ssc = 8 * (scg ^ (srow & 7));
  const __bf16* kG0 = kbase + (size_t)srow * 3072 + ssc;
  const __bf16* vG0 = vbase + (size_t)srow * SS + ssc;

  f32x16 o0 = {0,0,0,0,0,0,0,0,0,0,0,0,0,0,0,0};
  f32x16 o1 = {0,0,0,0,0,0,0,0,0,0,0,0,0,0,0,0};
  float mB = -INFINITY, lsum = 0.f;

  const int nkt = 2 * (qt + 1);

  // prologue: stage tile 0 into buf 0
  gld_lds16(kG0, lK[0] + tid * 8);
  gld_lds16(kG0 + (size_t)32 * 3072, lK[0] + tid * 8 + 2048);
  gld_lds16(vG0, lV[0] + tid * 8);
  gld_lds16(vG0 + (size_t)32 * SS, lV[0] + tid * 8 + 2048);
  __syncthreads();

  for (int kt = 0; kt < nkt; ++kt) {
    const int buf = kt & 1;
    const int kvb = kt * 64;
    if (kt + 1 < nkt) {  // prefetch next tile into other buffer
      const __bf16* kG = kG0 + (size_t)(kvb + 64) * 3072;
      const __bf16* vG = vG0 + (kvb + 64);
      gld_lds16(kG, lK[buf ^ 1] + tid * 8);
      gld_lds16(kG + (size_t)32 * 3072, lK[buf ^ 1] + tid * 8 + 2048);
      gld_lds16(vG, lV[buf ^ 1] + tid * 8);
      gld_lds16(vG + (size_t)32 * SS, lV[buf ^ 1] + tid * 8 + 2048);
    }

    if (kvb <= qw0 + 31) {  // wave-active (wave-uniform)
      // ---- QK^T: S^T[64 kv][32 q] = K-tile * Q^T, contract d=64 ----
      f32x16 s0 = {0,0,0,0,0,0,0,0,0,0,0,0,0,0,0,0};
      f32x16 s1 = {0,0,0,0,0,0,0,0,0,0,0,0,0,0,0,0};
      __builtin_amdgcn_s_setprio(1);
#pragma unroll
      for (int slot = 0; slot < 4; ++slot) {
        const int swz = 8 * ((slot * 2 + hi) ^ (q32 & 7));
        bf16x8 k0 = *reinterpret_cast<const bf16x8*>(lK[buf] + q32 * 64 + swz);
        bf16x8 k1 = *reinterpret_cast<const bf16x8*>(lK[buf] + (32 + q32) * 64 + swz);
        s0 = mfma32(k0, qb[slot], s0);
        s1 = mfma32(k1, qb[slot], s1);
      }
      __builtin_amdgcn_s_setprio(0);

      // ---- causal mask (only diagonal-region tiles) ----
      if (kvb + 63 > qw0) {
#pragma unroll
        for (int r = 0; r < 16; ++r) {
          const int rowc = (r & 3) + 8 * (r >> 2) + 4 * hi;
          if (kvb + rowc > q) s0[r] = -INFINITY;
          if (kvb + 32 + rowc > q) s1[r] = -INFINITY;
        }
      }

      // ---- online softmax, lane-local row ----
      float pm = s0[0];
#pragma unroll
      for (int r = 1; r < 16; ++r) pm = fmaxf(pm, s0[r]);
#pragma unroll
      for (int r = 0; r < 16; ++r) pm = fmaxf(pm, s1[r]);
      pm = fmaxf(pm, __shfl_xor(pm, 32));
      const float mnB = fmaxf(mB, pm * CEXP);
      const float alpha = EXP2F(mB - mnB);
      mB = mnB;
      float rs = 0.f;
#pragma unroll
      for (int r = 0; r < 16; ++r) {
        s0[r] = EXP2F(fmaf(s0[r], CEXP, -mnB));
        rs += s0[r];
      }
#pragma unroll
      for (int r = 0; r < 16; ++r) {
        s1[r] = EXP2F(fmaf(s1[r], CEXP, -mnB));
        rs += s1[r];
      }
      rs += __shfl_xor(rs, 32);
      lsum = lsum * alpha + rs;
#pragma unroll
      for (int r = 0; r < 16; ++r) { o0[r] *= alpha; o1[r] *= alpha; }

      // ---- P -> bf16 PV fragments (cvt_pk + permlane32_swap) ----
      bf16x8 pb[4];
      {
        unsigned int A = cvtpk_bf16(s0[0], s0[1]), B2 = cvtpk_bf16(s0[2], s0[3]);
        unsigned int C2 = cvtpk_bf16(s0[4], s0[5]), D2 = cvtpk_bf16(s0[6], s0[7]);
        swap32(A, C2); swap32(B2, D2);
        u32x4 t0 = {A, B2, C2, D2};
        pb[0] = __builtin_bit_cast(bf16x8, t0);
        unsigned int E = cvtpk_bf16(s0[8], s0[9]), F = cvtpk_bf16(s0[10], s0[11]);
        unsigned int G = cvtpk_bf16(s0[12], s0[13]), H = cvtpk_bf16(s0[14], s0[15]);
        swap32(E, G); swap32(F, H);
        u32x4 t1 = {E, F, G, H};
        pb[1] = __builtin_bit_cast(bf16x8, t1);
        unsigned int A3 = cvtpk_bf16(s1[0], s1[1]), B3 = cvtpk_bf16(s1[2], s1[3]);
        unsigned int C3 = cvtpk_bf16(s1[4], s1[5]), D3 = cvtpk_bf16(s1[6], s1[7]);
        swap32(A3, C3); swap32(B3, D3);
        u32x4 t2 = {A3, B3, C3, D3};
        pb[2] = __builtin_bit_cast(bf16x8, t2);
        unsigned int E3 = cvtpk_bf16(s1[8], s1[9]), F3 = cvtpk_bf16(s1[10], s1[11]);
        unsigned int G3 = cvtpk_bf16(s1[12], s1[13]), H3 = cvtpk_bf16(s1[14], s1[15]);
        swap32(E3, G3); swap32(F3, H3);
        u32x4 t3 = {E3, F3, G3, H3};
        pb[3] = __builtin_bit_cast(bf16x8, t3);
      }

      // ---- PV: O^T[64 d][32 q] += V^T-slot * P^T-slot ----
      __builtin_amdgcn_s_setprio(1);
#pragma unroll
      for (int slot = 0; slot < 4; ++slot) {
        const int swz = 8 * ((slot * 2 + hi) ^ (q32 & 7));
        bf16x8 v0 = *reinterpret_cast<const bf16x8*>(lV[buf] + q32 * 64 + swz);
        bf16x8 v1 = *reinterpret_cast<const bf16x8*>(lV[buf] + (32 + q32) * 64 + swz);
        o0 = mfma32(v0, pb[slot], o0);
        o1 = mfma32(v1, pb[slot], o1);
      }
      __builtin_amdgcn_s_setprio(0);
    }
    __syncthreads();  // staged loads drained + all waves done with buf
  }

  // ---- epilogue: O^T/lsum -> per-wave LDS transpose -> coalesced stores ----
  const float inv = 1.0f / lsum;
  __bf16* ol = lO[wave];
#pragma unroll
  for (int r = 0; r < 16; ++r) {
    const int d = (r & 3) + 8 * (r >> 2) + 4 * hi;
    ol[q32 * 72 + d] = (__bf16)(o0[r] * inv);
    ol[q32 * 72 + 32 + d] = (__bf16)(o1[r] * inv);
  }
  // per-wave buffer: no barrier needed (compiler inserts lgkmcnt waits)
#pragma unroll
  for (int pass = 0; pass < 4; ++pass) {
    const int idx = pass * 64 + lane;
    const int row = idx >> 3, colc = idx & 7;
    bf16x8 v = *reinterpret_cast<const bf16x8*>(ol + row * 72 + colc * 8);
    *reinterpret_cast<bf16x8*>(
        AO + (size_t)(b * SS + qt * 128 + wave * 32 + row) * 1024 + h * 64 + colc * 8) = v;
  }
}

extern "C" void kernel_launch(void* const* d_in, const int* in_sizes, int n_in,
                              void* d_out, int out_size, void* d_ws, size_t ws_size,
                              hipStream_t stream) {
  const float* x  = (const float*)d_in[0];
  const int* pos  = (const int*)d_in[1];
  const float* Wq = (const float*)d_in[2];
  const float* Wk = (const float*)d_in[3];
  const float* Wv = (const float*)d_in[4];
  const float* Wo = (const float*)d_in[5];

  __bf16* xb  = (__bf16*)d_ws;                        // [4096][1024]
  __bf16* Wb  = xb + (size_t)4096 * 1024;             // [4096][1024] = Wq;Wk;Wv;Wo stacked
  __bf16* qkv = Wb + (size_t)4096 * 1024;             // [4096][3072] (q|k|v cols)
  __bf16* Vt  = qkv + (size_t)4096 * 3072;            // [2*16*64][2048]
  __bf16* ao  = Vt + (size_t)2048 * 2048;             // [4096][1024]
  float2* tab = (float2*)(ao + (size_t)4096 * 1024);  // [2048*32]

  cvt8_kernel<<<2048, 256, 0, stream>>>(x, xb, 4096 * 1024);
  cvt8_kernel<<<512, 256, 0, stream>>>(Wq, Wb, 1024 * 1024);
  cvt8_kernel<<<512, 256, 0, stream>>>(Wk, Wb + (size_t)1024 * 1024, 1024 * 1024);
  cvt8_kernel<<<512, 256, 0, stream>>>(Wv, Wb + (size_t)2 * 1024 * 1024, 1024 * 1024);
  cvt8_kernel<<<512, 256, 0, stream>>>(Wo, Wb + (size_t)3 * 1024 * 1024, 1024 * 1024);
  trig_kernel<<<256, 256, 0, stream>>>(pos, tab);

  gemm_bt_kernel<__bf16><<<dim3(24, 32), 256, 0, stream>>>(xb, Wb, qkv, 4096, 3072, 1024);
  rope_kernel<<<16384, 256, 0, stream>>>(qkv, tab);
  vtrans_kernel<<<dim3(32, 16, 2), 256, 0, stream>>>(qkv, Vt);
  attn_kernel<<<dim3(16, 16, 2), 256, 0, stream>>>(qkv, Vt, ao);
  gemm_bt_kernel<float><<<dim3(8, 32), 256, 0, stream>>>(ao, Wb + (size_t)3 * 1024 * 1024,
                                                         (float*)d_out, 4096, 1024, 1024);
}